// Round 14
// baseline (573.100 us; speedup 1.0000x reference)
//
#include <hip/hip_runtime.h>
#include <hip/hip_bf16.h>

// CrossAttention: B=4, C=256, N=4096, OUT=256, temp=16.
// v13 (resubmit — r13 bench hit GPUAcquisitionTimeout, never ran).
// Two kernels (r12 proved residual ~86us is FIXED harness cost; proj ~12us).
//  - qkv_proj: r10 verbatim.
//  - flash: K AND V via REGISTER double-buffer prefetch straight from the
//    fragment-tiled global layouts (no K/V LDS at all). LDS = ps + lsum
//    (19.5KB). launch_bounds(512,1): r11's spill was the (512,2) 128-VGPR
//    cap; producer path ~220 VGPR fits the 256 cap.
//  - 4P+4C wave specialization, 1 barrier/interval, XCD-pinned b = x>>1,
//    in-kernel normalize (no-max softmax, |logit| <= ~2.5).
// Workspace: qg 8.4MB + kt 8.4MB + vt 8.4MB.

typedef __attribute__((ext_vector_type(8))) short bf16x8;
typedef __attribute__((ext_vector_type(4))) float f32x4;
typedef __attribute__((ext_vector_type(4))) short short4t;

constexpr int B_ = 4;
constexpr int C_ = 256;
constexpr int N_ = 4096;
constexpr int O_ = 256;
constexpr float INV_TEMP = 1.0f / 16.0f;
constexpr int NIT = 64;   // 64-key intervals (all 4096 keys)

__device__ __forceinline__ short f2bf(float f) {
  union { float f; unsigned u; } v; v.f = f;
  unsigned r = v.u + 0x7fffu + ((v.u >> 16) & 1u);   // RNE
  return (short)(r >> 16);
}

// ---------------------------------------------------------------------------
// Projections (r10 verbatim). Grid (64, B, 3). Block 256. z: 0=Q, 1=K, 2=V.
// ---------------------------------------------------------------------------
__global__ __launch_bounds__(256, 2) void qkv_proj(
    const float* __restrict__ x, const float* __restrict__ xx,
    const float* __restrict__ Wq, const float* __restrict__ Wk,
    const float* __restrict__ Wv,
    short* __restrict__ qg, short* __restrict__ kt, short* __restrict__ vt) {
  const int n0  = blockIdx.x * 64;
  const int b   = blockIdx.y;
  const int mat = blockIdx.z;
  const float* src = (mat == 0) ? x : xx;
  const float* Wm  = (mat == 0) ? Wq : (mat == 1 ? Wk : Wv);
  const float ws   = (mat == 0) ? INV_TEMP : 1.0f;
  const int tid = threadIdx.x;
  const int w = tid >> 6, lane = tid & 63;
  const int g = lane >> 4, c16 = lane & 15;

  __shared__ __align__(16) short xs[64][264];   // staged tile / out assembly

  {  // transpose staging: coalesced dword loads along n, short4 LDS writes
    const int n = tid & 63, cq = tid >> 6;
    const float* sp = src + (size_t)b * C_ * N_ + n0 + n;
#pragma unroll
    for (int rep = 0; rep < 16; ++rep) {
      int c = rep * 16 + cq * 4;
      short4t s4;
#pragma unroll
      for (int j = 0; j < 4; ++j) s4[j] = f2bf(sp[(size_t)(c + j) * N_]);
      *(short4t*)&xs[n][c] = s4;
    }
  }
  __syncthreads();

  f32x4 acc[4][4];
#pragma unroll
  for (int i = 0; i < 4; ++i)
#pragma unroll
    for (int j = 0; j < 4; ++j) acc[i][j] = (f32x4){0.f, 0.f, 0.f, 0.f};

#pragma unroll
  for (int ko = 0; ko < 8; ++ko) {
    bf16x8 wfr[4], xfr[4];
#pragma unroll
    for (int ot = 0; ot < 4; ++ot) {
      const float* wp =
          Wm + (size_t)(w * 64 + ot * 16 + c16) * C_ + ko * 32 + g * 8;
      float4 f0 = *(const float4*)wp;
      float4 f1 = *(const float4*)(wp + 4);
      bf16x8 a;
      a[0] = f2bf(f0.x * ws); a[1] = f2bf(f0.y * ws);
      a[2] = f2bf(f0.z * ws); a[3] = f2bf(f0.w * ws);
      a[4] = f2bf(f1.x * ws); a[5] = f2bf(f1.y * ws);
      a[6] = f2bf(f1.z * ws); a[7] = f2bf(f1.w * ws);
      wfr[ot] = a;
    }
#pragma unroll
    for (int nt = 0; nt < 4; ++nt)
      xfr[nt] = *(const bf16x8*)&xs[nt * 16 + c16][ko * 32 + g * 8];
    if (mat < 2) {
#pragma unroll
      for (int ot = 0; ot < 4; ++ot)
#pragma unroll
        for (int nt = 0; nt < 4; ++nt)
          acc[ot][nt] = __builtin_amdgcn_mfma_f32_16x16x32_bf16(
              wfr[ot], xfr[nt], acc[ot][nt], 0, 0, 0);
    } else {  // V: swapped operands -> D rows = m, cols = o
#pragma unroll
      for (int mt = 0; mt < 4; ++mt)
#pragma unroll
        for (int ot = 0; ot < 4; ++ot)
          acc[mt][ot] = __builtin_amdgcn_mfma_f32_16x16x32_bf16(
              xfr[mt], wfr[ot], acc[mt][ot], 0, 0, 0);
    }
  }

  __syncthreads();               // xs tile reads done; reuse as out-assembly
  short* ob = &xs[0][0];         // 16384 shorts used

  if (mat == 0) {
#pragma unroll
    for (int ot = 0; ot < 4; ++ot)
#pragma unroll
      for (int nt = 0; nt < 4; ++nt) {
        int f = (nt * 16 + c16) * 256 + w * 64 + ot * 16 + g * 4;
        short4t s;
        s[0] = f2bf(acc[ot][nt][0]);
        s[1] = f2bf(acc[ot][nt][1]);
        s[2] = f2bf(acc[ot][nt][2]);
        s[3] = f2bf(acc[ot][nt][3]);
        *(short4t*)&ob[f] = s;
      }
  } else if (mat == 1) {
#pragma unroll
    for (int ot = 0; ot < 4; ++ot)
#pragma unroll
      for (int nt = 0; nt < 4; ++nt) {
        int koo = w * 2 + (ot >> 1);
        int pos = (((ot & 1) * 2 + (g >> 1)) ^ ((c16 >> 1) & 3));
        int f = nt * 4096 + koo * 512 + c16 * 32 + pos * 8 + (g & 1) * 4;
        short4t s;
        s[0] = f2bf(acc[ot][nt][0]);
        s[1] = f2bf(acc[ot][nt][1]);
        s[2] = f2bf(acc[ot][nt][2]);
        s[3] = f2bf(acc[ot][nt][3]);
        *(short4t*)&ob[f] = s;
      }
  } else {  // V: acc[mt][ot], rows m = mt*16+g*4+r, cols o = w*64+ot*16+c16
#pragma unroll
    for (int mt = 0; mt < 4; ++mt)
#pragma unroll
      for (int ot = 0; ot < 4; ++ot) {
        int o = w * 64 + ot * 16 + c16;
        int pos = (mt * 2 + (g >> 1)) ^ (o & 7);
        int f = o * 64 + pos * 8 + (g & 1) * 4;
        short4t s;
        s[0] = f2bf(acc[mt][ot][0]);
        s[1] = f2bf(acc[mt][ot][1]);
        s[2] = f2bf(acc[mt][ot][2]);
        s[3] = f2bf(acc[mt][ot][3]);
        *(short4t*)&ob[f] = s;
      }
  }
  __syncthreads();

  short* dst = (mat == 0) ? qg + ((size_t)b * N_ + n0) * O_
             : (mat == 1) ? kt + (size_t)(b * 256 + (n0 >> 4)) * 4096
                          : vt + (size_t)(b * 64 + (n0 >> 6)) * 16384;
  const uint4* s4 = (const uint4*)ob;
  uint4* d4 = (uint4*)dst;
#pragma unroll
  for (int j = 0; j < 8; ++j) d4[j * 256 + tid] = s4[j * 256 + tid];
}

// ---------------------------------------------------------------------------
// Flash attention. Grid (8, 32). Block 512 (4 producers + 4 consumers).
// K and V fragments register-double-buffered straight from global (layouts
// are fragment-tiled + swizzled). LDS: ps 18KB + lsum 1KB only.
// ---------------------------------------------------------------------------
#define PSTEP(I, CUR)                                                        \
  if (prod) {                                                                \
    if ((I) < NIT) {                                                         \
      if ((I) + 1 < NIT) { /* K(I+1) granule pw -> kreg[CUR^1] */            \
        const short* src = ktb + (size_t)(4 * ((I) + 1) + pw) * 4096;        \
        _Pragma("unroll")                                                    \
        for (int ko = 0; ko < 8; ++ko)                                       \
          kreg[(CUR) ^ 1][ko] =                                              \
              *(const bf16x8*)&src[(ko * 16 + c16) * 32 + sw];               \
      }                                                                      \
      f32x4 sacc[4];                                                         \
      _Pragma("unroll")                                                      \
      for (int nt = 0; nt < 4; ++nt) sacc[nt] = (f32x4){0.f, 0.f, 0.f, 0.f};\
      _Pragma("unroll")                                                      \
      for (int ko = 0; ko < 8; ++ko) {                                       \
        bf16x8 kf = kreg[(CUR)][ko];                                         \
        _Pragma("unroll")                                                    \
        for (int nt = 0; nt < 4; ++nt)                                       \
          sacc[nt] = __builtin_amdgcn_mfma_f32_16x16x32_bf16(                \
              kf, qf[nt][ko], sacc[nt], 0, 0, 0);                            \
      }                                                                      \
      _Pragma("unroll")                                                      \
      for (int nt = 0; nt < 4; ++nt) {                                       \
        short4t pb;                                                          \
        float rs = 0.f;                                                      \
        _Pragma("unroll")                                                    \
        for (int r = 0; r < 4; ++r) {                                        \
          float p = __expf(sacc[nt][r]);                                     \
          rs += p;                                                           \
          pb[r] = f2bf(p);                                                   \
        }                                                                    \
        lrun[nt] += rs;                                                      \
        *(short4t*)&ps[(CUR)][nt * 16 + c16][pw * 16 + g * 4] = pb;          \
      }                                                                      \
    }                                                                        \
  } else {                                                                   \
    if ((I) < NIT) { /* V(I) o-slice pw -> vreg[CUR] */                      \
      const short* vsrc = vtb + (size_t)(I) * 16384 + pw * 4096;             \
      _Pragma("unroll")                                                      \
      for (int ot = 0; ot < 4; ++ot)                                         \
        _Pragma("unroll")                                                    \
        for (int kk = 0; kk < 2; ++kk)                                       \
          vreg[(CUR)][ot * 2 + kk] = *(const bf16x8*)                        \
              &vsrc[(ot * 16 + c16) * 64 + (((kk * 4 + g) ^ (c16 & 7)) * 8)];\
    }                                                                        \
    if ((I) > 0) { /* O += V(I-1) P(I-1)^T for o-slice pw */                 \
      _Pragma("unroll")                                                      \
      for (int kk = 0; kk < 2; ++kk) {                                       \
        bf16x8 pf[4];                                                        \
        _Pragma("unroll")                                                    \
        for (int nt = 0; nt < 4; ++nt)                                       \
          pf[nt] = *(const bf16x8*)                                          \
              &ps[(CUR) ^ 1][nt * 16 + c16][kk * 32 + g * 8];                \
        _Pragma("unroll")                                                    \
        for (int ot = 0; ot < 4; ++ot) {                                     \
          bf16x8 vf = vreg[(CUR) ^ 1][ot * 2 + kk];                          \
          _Pragma("unroll")                                                  \
          for (int nt = 0; nt < 4; ++nt)                                     \
            oacc[ot][nt] = __builtin_amdgcn_mfma_f32_16x16x32_bf16(          \
                vf, pf[nt], oacc[ot][nt], 0, 0, 0);                          \
        }                                                                    \
      }                                                                      \
    }                                                                        \
  }

__global__ __launch_bounds__(512, 1) void flash_attn(
    const short* __restrict__ qg, const short* __restrict__ kt,
    const short* __restrict__ vt, float* __restrict__ out) {
  const int xg = blockIdx.x;
  const int b  = xg >> 1;
  const int n0 = (((xg & 1) << 5) + blockIdx.y) * 64;
  const int tid = threadIdx.x;
  const int w = tid >> 6, lane = tid & 63;
  const int g = lane >> 4, c16 = lane & 15;
  const bool prod = (w < 4);
  const int pw = w & 3;            // producer granule / consumer o-slice

  __shared__ short ps[2][64][72];  // P dbuf: 64 n x 64 m (18 KB)
  __shared__ float lsum[4][64];

  const short* ktb = kt + (size_t)b * N_ * O_;
  const short* vtb = vt + (size_t)b * N_ * O_;

  const int sw = (g ^ ((c16 >> 1) & 3)) * 8;   // K chunk swizzle (shorts)

  bf16x8 qf[4][8];                 // producers: 64 n x 256 o   (128 regs)
  bf16x8 kreg[2][8];               // producers: K frag dbuf     (64 regs)
  bf16x8 vreg[2][8];               // consumers: V frag dbuf     (64 regs)
  float lrun[4] = {0.f, 0.f, 0.f, 0.f};
  f32x4 oacc[4][4];
#pragma unroll
  for (int i = 0; i < 4; ++i)
#pragma unroll
    for (int j = 0; j < 4; ++j) oacc[i][j] = (f32x4){0.f, 0.f, 0.f, 0.f};

  if (prod) {
#pragma unroll
    for (int nt = 0; nt < 4; ++nt) {
      const short* qrow =
          qg + (size_t)(b * N_ + n0 + nt * 16 + c16) * O_ + g * 8;
#pragma unroll
      for (int ko = 0; ko < 8; ++ko)
        qf[nt][ko] = *(const bf16x8*)(qrow + ko * 32);
    }
    // prologue: K(0) granule pw -> kreg[0]
    const short* src = ktb + (size_t)pw * 4096;
#pragma unroll
    for (int ko = 0; ko < 8; ++ko)
      kreg[0][ko] = *(const bf16x8*)&src[(ko * 16 + c16) * 32 + sw];
  }

  for (int ih = 0; ih < NIT / 2; ++ih) {
    PSTEP(2 * ih, 0);
    __syncthreads();
    PSTEP(2 * ih + 1, 1);
    __syncthreads();
  }
  PSTEP(NIT, 0);   // tail: consumers drain PV(NIT-1); producers idle
  __syncthreads();

  // epilogue: producers publish granule row-sums; consumers normalize+store
  if (prod) {
#pragma unroll
    for (int nt = 0; nt < 4; ++nt) {
      float v = lrun[nt];
      v += __shfl_xor(v, 16);
      v += __shfl_xor(v, 32);
      if (lane < 16) lsum[pw][nt * 16 + lane] = v;
    }
  }
  __syncthreads();
  if (!prod) {
#pragma unroll
    for (int nt = 0; nt < 4; ++nt) {
      const int nl = nt * 16 + c16;
      float l = lsum[0][nl] + lsum[1][nl] + lsum[2][nl] + lsum[3][nl];
      float li = 1.0f / l;
#pragma unroll
      for (int ot = 0; ot < 4; ++ot) {
        float* op = out + ((size_t)b * O_ + pw * 64 + ot * 16 + g * 4) * N_ +
                    n0 + nl;
#pragma unroll
        for (int r = 0; r < 4; ++r)
          op[(size_t)r * N_] = oacc[ot][nt][r] * li;
      }
    }
  }
}

// ---------------------------------------------------------------------------
extern "C" void kernel_launch(void* const* d_in, const int* in_sizes, int n_in,
                              void* d_out, int out_size, void* d_ws,
                              size_t ws_size, hipStream_t stream) {
  const float* x  = (const float*)d_in[0];
  const float* xx = (const float*)d_in[1];
  const float* Wq = (const float*)d_in[2];
  const float* Wk = (const float*)d_in[3];
  const float* Wv = (const float*)d_in[4];
  float* out = (float*)d_out;

  short* qg = (short*)d_ws;                         // 8.39 MB
  short* kt = qg + (size_t)B_ * N_ * O_;            // 8.39 MB (tiled K)
  short* vt = kt + (size_t)B_ * N_ * O_;            // 8.39 MB (tiled V)

  qkv_proj<<<dim3(N_ / 64, B_, 3), 256, 0, stream>>>(x, xx, Wq, Wk, Wv, qg,
                                                     kt, vt);
  flash_attn<<<dim3(8, 32), 512, 0, stream>>>(qg, kt, vt, out);
}